// Round 4
// baseline (2372.726 us; speedup 1.0000x reference)
//
#include <hip/hip_runtime.h>
#include <hip/hip_bf16.h>

typedef unsigned int uint32;

typedef __bf16 bf16x8 __attribute__((ext_vector_type(8)));
typedef float f32x4 __attribute__((ext_vector_type(4)));

static __device__ __forceinline__ ushort f2bf(float f) {
    union { __hip_bfloat16 h; ushort u; } c;
    c.h = __float2bfloat16(f);
    return c.u;
}
static __device__ __forceinline__ float bflo(uint32 u) {
    return __builtin_bit_cast(float, (uint32)(u << 16));
}
static __device__ __forceinline__ float bfhi(uint32 u) {
    return __builtin_bit_cast(float, (uint32)(u & 0xffff0000u));
}

// ---------------------------------------------------------------- pre-passes

__global__ __launch_bounds__(256) void cvt_bf16(const float* __restrict__ in,
                                                ushort* __restrict__ out, int n4) {
    int i = blockIdx.x * 256 + threadIdx.x;
    if (i >= n4) return;
    float4 v = reinterpret_cast<const float4*>(in)[i];
    ushort4 o;
    o.x = f2bf(v.x); o.y = f2bf(v.y); o.z = f2bf(v.z); o.w = f2bf(v.w);
    reinterpret_cast<ushort4*>(out)[i] = o;
}

// W [K,N] f32  ->  WT [N,K] bf16  (32x32 LDS tile transpose)
__global__ __launch_bounds__(256) void wtrans(const float* __restrict__ W,
                                              ushort* __restrict__ WT, int K, int N) {
    __shared__ float tile[32][33];
    int n0 = blockIdx.x * 32, k0 = blockIdx.y * 32;
    int tx = threadIdx.x, ty = threadIdx.y;   // 32 x 8
    #pragma unroll
    for (int r = 0; r < 32; r += 8)
        tile[ty + r][tx] = W[(size_t)(k0 + ty + r) * N + n0 + tx];
    __syncthreads();
    #pragma unroll
    for (int r = 0; r < 32; r += 8)
        WT[(size_t)(n0 + ty + r) * K + k0 + tx] = f2bf(tile[tx][ty + r]);
}

// ---------------------------------------------------------------- GEMM (m97 structure)
// C[M,N] = A[M,K] * BT[N,K]^T   (all bf16, fp32 accum), optional fp32 bias[col]

__device__ __forceinline__ void gload16(void* lds, const void* g) {
    __builtin_amdgcn_global_load_lds(
        (const __attribute__((address_space(1))) unsigned int*)g,
        (__attribute__((address_space(3))) unsigned int*)lds, 16, 0, 0);
}

__global__ __launch_bounds__(256) void gemm_bt(
        const ushort* __restrict__ A, int lda,
        const ushort* __restrict__ BT,
        const float* __restrict__ bias,
        ushort* __restrict__ C, int ldc, int K) {
    __shared__ ushort lsA[128 * 32];
    __shared__ ushort lsB[128 * 32];
    const int t = threadIdx.x;
    const int wid = t >> 6, lane = t & 63;
    const int wr = wid >> 1, wc = wid & 1;       // 2x2 waves of 64x64
    const size_t m0 = (size_t)blockIdx.y * 128;
    const size_t n0 = (size_t)blockIdx.x * 128;
    const int lrow = lane & 15, lk = lane >> 4;
    f32x4 acc[4][4] = {};

    for (int kt = 0; kt < K; kt += 32) {
        #pragma unroll
        for (int q = 0; q < 2; ++q) {
            int c = t + q * 256;                 // 16-byte chunk id (0..511)
            int by = c * 16;                     // byte offset inside 8KB tile
            int row = by >> 6;                   // 64 B per row (32 bf16)
            int colb = by & 63;
            gload16((char*)lsA + by, (const char*)(A + (m0 + row) * (size_t)lda + kt) + colb);
            gload16((char*)lsB + by, (const char*)(BT + (n0 + row) * (size_t)K + kt) + colb);
        }
        __syncthreads();
        bf16x8 fa[4], fb[4];
        #pragma unroll
        for (int m = 0; m < 4; ++m)
            fa[m] = *reinterpret_cast<const bf16x8*>(&lsA[(wr * 64 + m * 16 + lrow) * 32 + lk * 8]);
        #pragma unroll
        for (int n = 0; n < 4; ++n)
            fb[n] = *reinterpret_cast<const bf16x8*>(&lsB[(wc * 64 + n * 16 + lrow) * 32 + lk * 8]);
        #pragma unroll
        for (int m = 0; m < 4; ++m)
            #pragma unroll
            for (int n = 0; n < 4; ++n)
                acc[m][n] = __builtin_amdgcn_mfma_f32_16x16x32_bf16(fa[m], fb[n], acc[m][n], 0, 0, 0);
        __syncthreads();
    }

    // C/D layout: col = lane&15, row = (lane>>4)*4 + r   [guide m89, verified]
    const size_t crow0 = m0 + wr * 64;
    const size_t ccol0 = n0 + wc * 64;
    #pragma unroll
    for (int n = 0; n < 4; ++n) {
        size_t col = ccol0 + n * 16 + lrow;
        float bv = bias ? bias[col] : 0.0f;
        #pragma unroll
        for (int m = 0; m < 4; ++m) {
            #pragma unroll
            for (int r = 0; r < 4; ++r) {
                size_t row = crow0 + m * 16 + lk * 4 + r;
                C[row * (size_t)ldc + col] = f2bf(acc[m][n][r] + bv);
            }
        }
    }
}

// ---------------------------------------------------------------- attention 1
// one wave per (local b, head). GL/GR: [3*Bc][1024] bf16 (row = b*3 + node)
__global__ __launch_bounds__(256) void attn1_k(
        const ushort* __restrict__ GL, const ushort* __restrict__ GR,
        const float* __restrict__ att,      // [8][128]
        const float* __restrict__ b1,       // [1024]
        ushort* __restrict__ X2) {          // [3*Bc][1024] bf16
    int task = blockIdx.x * 4 + (threadIdx.x >> 6);
    int lane = threadIdx.x & 63;
    int b = task >> 3, h = task & 7;
    size_t roff = (size_t)b * 3 * 1024 + h * 128 + lane * 2;

    float gl[3][2], gr[3][2];
    #pragma unroll
    for (int j = 0; j < 3; ++j) {
        uint32 u = *reinterpret_cast<const uint32*>(GL + roff + (size_t)j * 1024);
        gl[j][0] = bflo(u); gl[j][1] = bfhi(u);
        uint32 v = *reinterpret_cast<const uint32*>(GR + roff + (size_t)j * 1024);
        gr[j][0] = bflo(v); gr[j][1] = bfhi(v);
    }
    float a0 = att[h * 128 + lane * 2], a1 = att[h * 128 + lane * 2 + 1];

    float e[3][3];
    #pragma unroll
    for (int i = 0; i < 3; ++i) {
        #pragma unroll
        for (int j = 0; j < 3; ++j) {
            float x0 = gl[j][0] + gr[i][0]; x0 = x0 > 0.0f ? x0 : 0.2f * x0;
            float x1 = gl[j][1] + gr[i][1]; x1 = x1 > 0.0f ? x1 : 0.2f * x1;
            float p = a0 * x0 + a1 * x1;
            #pragma unroll
            for (int s = 1; s < 64; s <<= 1) p += __shfl_xor(p, s);
            e[i][j] = p;
        }
    }
    #pragma unroll
    for (int i = 0; i < 3; ++i) {
        float mx = fmaxf(e[i][0], fmaxf(e[i][1], e[i][2]));
        float w0 = __expf(e[i][0] - mx), w1 = __expf(e[i][1] - mx), w2 = __expf(e[i][2] - mx);
        float inv = 1.0f / (w0 + w1 + w2);
        float o0 = (w0 * gl[0][0] + w1 * gl[1][0] + w2 * gl[2][0]) * inv + b1[h * 128 + lane * 2];
        float o1 = (w0 * gl[0][1] + w1 * gl[1][1] + w2 * gl[2][1]) * inv + b1[h * 128 + lane * 2 + 1];
        o0 = o0 > 0.0f ? o0 : __expf(o0) - 1.0f;   // ELU(alpha=1)
        o1 = o1 > 0.0f ? o1 : __expf(o1) - 1.0f;
        uint32 pk = ((uint32)f2bf(o1) << 16) | (uint32)f2bf(o0);
        *reinterpret_cast<uint32*>(X2 + ((size_t)b * 3 + i) * 1024 + h * 128 + lane * 2) = pk;
    }
}

// ---------------------------------------------------------------- attention 2 + mean pool
__device__ __forceinline__ void unpack8(uint4 u, float* f) {
    f[0] = bflo(u.x); f[1] = bfhi(u.x); f[2] = bflo(u.y); f[3] = bfhi(u.y);
    f[4] = bflo(u.z); f[5] = bfhi(u.z); f[6] = bflo(u.w); f[7] = bfhi(u.w);
}

// one wave per local b. GL/GR: [3*Bc][1024] bf16
__global__ __launch_bounds__(256) void attn2_k(
        const ushort* __restrict__ GL, const ushort* __restrict__ GR,
        const float* __restrict__ att,      // [1024]
        const float* __restrict__ b2,       // [1024]
        float* __restrict__ out) {          // [Bc][1024] f32 (already offset)
    int b = blockIdx.x * 4 + (threadIdx.x >> 6);
    int lane = threadIdx.x & 63;
    int c0 = lane * 16;
    const ushort* bl = GL + (size_t)b * 3 * 1024 + c0;
    const ushort* br = GR + (size_t)b * 3 * 1024 + c0;

    float gl[3][16], gr[3][16];
    #pragma unroll
    for (int j = 0; j < 3; ++j) {
        const uint4* p = reinterpret_cast<const uint4*>(bl + (size_t)j * 1024);
        unpack8(p[0], &gl[j][0]); unpack8(p[1], &gl[j][8]);
        const uint4* q = reinterpret_cast<const uint4*>(br + (size_t)j * 1024);
        unpack8(q[0], &gr[j][0]); unpack8(q[1], &gr[j][8]);
    }
    float av[16];
    #pragma unroll
    for (int t4 = 0; t4 < 4; ++t4) {
        float4 a = reinterpret_cast<const float4*>(att + c0)[t4];
        av[t4 * 4 + 0] = a.x; av[t4 * 4 + 1] = a.y; av[t4 * 4 + 2] = a.z; av[t4 * 4 + 3] = a.w;
    }

    float e[3][3];
    #pragma unroll
    for (int i = 0; i < 3; ++i) {
        #pragma unroll
        for (int j = 0; j < 3; ++j) {
            float p = 0.0f;
            #pragma unroll
            for (int t = 0; t < 16; ++t) {
                float x = gl[j][t] + gr[i][t];
                x = x > 0.0f ? x : 0.2f * x;
                p += av[t] * x;
            }
            #pragma unroll
            for (int s = 1; s < 64; s <<= 1) p += __shfl_xor(p, s);
            e[i][j] = p;
        }
    }
    float fo[16];
    #pragma unroll
    for (int t = 0; t < 16; ++t) fo[t] = 0.0f;
    #pragma unroll
    for (int i = 0; i < 3; ++i) {
        float mx = fmaxf(e[i][0], fmaxf(e[i][1], e[i][2]));
        float w0 = __expf(e[i][0] - mx), w1 = __expf(e[i][1] - mx), w2 = __expf(e[i][2] - mx);
        float inv = 1.0f / (w0 + w1 + w2);
        #pragma unroll
        for (int t = 0; t < 16; ++t)
            fo[t] += (w0 * gl[0][t] + w1 * gl[1][t] + w2 * gl[2][t]) * inv;
    }
    const float third = 1.0f / 3.0f;
    #pragma unroll
    for (int t4 = 0; t4 < 4; ++t4) {
        float4 bb = reinterpret_cast<const float4*>(b2 + c0)[t4];
        float4 o;
        o.x = fo[t4 * 4 + 0] * third + bb.x;
        o.y = fo[t4 * 4 + 1] * third + bb.y;
        o.z = fo[t4 * 4 + 2] * third + bb.z;
        o.w = fo[t4 * 4 + 3] * third + bb.w;
        reinterpret_cast<float4*>(out + (size_t)b * 1024 + c0)[t4] = o;
    }
}

// ---------------------------------------------------------------- launch

extern "C" void kernel_launch(void* const* d_in, const int* in_sizes, int n_in,
                              void* d_out, int out_size, void* d_ws, size_t ws_size,
                              hipStream_t stream) {
    const int B = 32768;
    const float* text  = (const float*)d_in[0];
    const float* audio = (const float*)d_in[1];
    const float* video = (const float*)d_in[2];
    const float* Wt  = (const float*)d_in[3];
    const float* bt  = (const float*)d_in[4];
    const float* Wa  = (const float*)d_in[5];
    const float* ba  = (const float*)d_in[6];
    const float* Wv  = (const float*)d_in[7];
    const float* bv  = (const float*)d_in[8];
    const float* Wl1 = (const float*)d_in[9];
    const float* Wr1 = (const float*)d_in[10];
    const float* att1 = (const float*)d_in[11];
    const float* b1  = (const float*)d_in[12];
    const float* Wl2 = (const float*)d_in[13];
    const float* Wr2 = (const float*)d_in[14];
    const float* att2 = (const float*)d_in[15];
    const float* b2  = (const float*)d_in[16];

    // --- workspace: 16 MiB weight area + 4 rotating activation regions.
    // Chunk count NC adapts to ws_size:  need = 16MiB + 4 * (3*Bc*1024*2B).
    char* ws = (char*)d_ws;
    ushort* WTt  = (ushort*)ws;
    ushort* WTa  = WTt  + (1u << 20);
    ushort* WTv  = WTa  + (1u << 20);
    ushort* WT1L = WTv  + (1u << 20);
    ushort* WT1R = WT1L + (1u << 20);
    ushort* WT2L = WT1R + (1u << 20);
    ushort* WT2R = WT2L + (1u << 20);
    const size_t WRES = (size_t)16 << 20;

    int NC = 1;
    while (NC < 256) {
        size_t need = WRES + (size_t)4 * 3 * (B / NC) * 1024 * 2;
        if (need <= ws_size) break;
        NC <<= 1;
    }
    const int Bc = B / NC;                      // batch rows per chunk (>=128)
    const size_t S = (size_t)3 * Bc * 1024;     // elements per activation region
    ushort* Abuf = (ushort*)(ws + WRES);
    ushort* Bbuf = Abuf + S;
    ushort* Cbuf = Bbuf + S;
    ushort* Dbuf = Cbuf + S;

    // weights: transpose + convert once
    {
        dim3 blk(32, 8), grd(32, 32);
        wtrans<<<grd, blk, 0, stream>>>(Wt,  WTt,  1024, 1024);
        wtrans<<<grd, blk, 0, stream>>>(Wa,  WTa,  1024, 1024);
        wtrans<<<grd, blk, 0, stream>>>(Wv,  WTv,  1024, 1024);
        wtrans<<<grd, blk, 0, stream>>>(Wl1, WT1L, 1024, 1024);
        wtrans<<<grd, blk, 0, stream>>>(Wr1, WT1R, 1024, 1024);
        wtrans<<<grd, blk, 0, stream>>>(Wl2, WT2L, 1024, 1024);
        wtrans<<<grd, blk, 0, stream>>>(Wr2, WT2R, 1024, 1024);
    }

    for (int c = 0; c < NC; ++c) {
        const size_t b0 = (size_t)c * Bc;
        // 1. features -> bf16 (modality-major inside Abuf)
        const int n4 = Bc * 256;                 // Bc*1024/4
        cvt_bf16<<<Bc, 256, 0, stream>>>(text  + b0 * 1024, Abuf + 0 * (size_t)Bc * 1024, n4);
        cvt_bf16<<<Bc, 256, 0, stream>>>(audio + b0 * 1024, Abuf + 1 * (size_t)Bc * 1024, n4);
        cvt_bf16<<<Bc, 256, 0, stream>>>(video + b0 * 1024, Abuf + 2 * (size_t)Bc * 1024, n4);
        // 2. projections -> X (node-interleaved rows, ldc=3072) in Bbuf
        {
            dim3 grd(8, Bc / 128);
            gemm_bt<<<grd, 256, 0, stream>>>(Abuf + 0 * (size_t)Bc * 1024, 1024, WTt, bt, Bbuf + 0 * 1024, 3072, 1024);
            gemm_bt<<<grd, 256, 0, stream>>>(Abuf + 1 * (size_t)Bc * 1024, 1024, WTa, ba, Bbuf + 1 * 1024, 3072, 1024);
            gemm_bt<<<grd, 256, 0, stream>>>(Abuf + 2 * (size_t)Bc * 1024, 1024, WTv, bv, Bbuf + 2 * 1024, 3072, 1024);
        }
        // 3. GATv2-1: GL1 -> Cbuf, GR1 -> Dbuf
        {
            dim3 grd(8, 3 * Bc / 128);
            gemm_bt<<<grd, 256, 0, stream>>>(Bbuf, 1024, WT1L, nullptr, Cbuf, 1024, 1024);
            gemm_bt<<<grd, 256, 0, stream>>>(Bbuf, 1024, WT1R, nullptr, Dbuf, 1024, 1024);
        }
        // 4. attention-1 + bias + ELU -> X2 in Abuf (Xbf dead)
        attn1_k<<<Bc * 2, 256, 0, stream>>>(Cbuf, Dbuf, att1, b1, Abuf);
        // 5. GATv2-2: GL2 -> Bbuf (X dead), GR2 -> Cbuf (GL1 dead)
        {
            dim3 grd(8, 3 * Bc / 128);
            gemm_bt<<<grd, 256, 0, stream>>>(Abuf, 1024, WT2L, nullptr, Bbuf, 1024, 1024);
            gemm_bt<<<grd, 256, 0, stream>>>(Abuf, 1024, WT2R, nullptr, Cbuf, 1024, 1024);
        }
        // 6. attention-2 + bias + mean pool -> f32 out
        attn2_k<<<Bc / 4, 256, 0, stream>>>(Bbuf, Cbuf, att2, b2, (float*)d_out + b0 * 1024);
    }
    (void)in_sizes; (void)n_in; (void)out_size;
}